// Round 1
// 1478.406 us; speedup vs baseline: 1.0219x; 1.0219x over previous
//
#include <hip/hip_runtime.h>
#include <math.h>

#define BB 256
#define TT 2048
#define HH 64

typedef _Float16 half2v __attribute__((ext_vector_type(2)));
typedef __fp16  fp16v2 __attribute__((ext_vector_type(2)));
union H2I { half2v h; int i; };

#if __has_builtin(__builtin_amdgcn_rcpf)
__device__ __forceinline__ float fast_rcp(float v) { return __builtin_amdgcn_rcpf(v); }
#else
__device__ __forceinline__ float fast_rcp(float v) { return 1.0f / v; }
#endif
#if __has_builtin(__builtin_amdgcn_rsqf)
__device__ __forceinline__ float fast_rsq(float v) { return __builtin_amdgcn_rsqf(v); }
#else
__device__ __forceinline__ float fast_rsq(float v) { return rsqrtf(v); }
#endif

__device__ __forceinline__ float tanh_fast(float v) {
    // tanh(x) = 1 - 2/(e^{2x}+1); saturates correctly at +/-inf
    float e = __expf(2.0f * v);
    return fmaf(-2.0f, fast_rcp(e + 1.0f), 1.0f);
}

__device__ __forceinline__ float sigmoid_fast(float v) {
    return fast_rcp(1.0f + __expf(-v));
}

__device__ __forceinline__ float fdot2(half2v a, half2v b, float c) {
    return __builtin_amdgcn_fdot2(a, b, c, false);
}

__device__ __forceinline__ half2v pack_pair(float a, float b) {
    fp16v2 r = __builtin_amdgcn_cvt_pkrtz(a, b);
    return __builtin_bit_cast(half2v, r);
}

// force a value to live in a VGPR across the loop (defeat load-rematerialization)
__device__ __forceinline__ void pin_h2(half2v& v) {
    H2I u; u.h = v;
    asm volatile("" : "+v"(u.i));
    v = u.h;
}

// broadcast a packed f16x2 from a wave-uniform lane index to all lanes (lands in SGPR)
__device__ __forceinline__ half2v bcast_pair(half2v v, int lane) {
    H2I u; u.h = v;
    H2I w; w.i = __builtin_amdgcn_readlane(u.i, lane);
    return w.h;
}

// neighbor value within a quad: lane j gets lane j^1 (DPP quad_perm [1,0,3,2])
__device__ __forceinline__ float dpp_neighbor(float v) {
    return __int_as_float(__builtin_amdgcn_mov_dpp(__float_as_int(v), 0xB1, 0xf, 0xf, true));
}

__global__ __launch_bounds__(64, 1)
void pgjanet_kernel(const float* __restrict__ x,
                    const float* __restrict__ h0,
                    const float* __restrict__ Wa,  const float* __restrict__ ba,
                    const float* __restrict__ Wp1, const float* __restrict__ bp1,
                    const float* __restrict__ Wp2, const float* __restrict__ bp2,
                    const float* __restrict__ Wf,  const float* __restrict__ bf,
                    const float* __restrict__ Wg,  const float* __restrict__ bg,
                    const float* __restrict__ Wo,  const float* __restrict__ bo,
                    float* __restrict__ out)
{
    const int b = blockIdx.x;
    const int j = threadIdx.x;   // 0..63 : hidden index, single wave per block

    __shared__ float xs[TT * 2];          // 16 KB staged input
    __shared__ float hbuf[64][HH + 1];    // 16.6 KB h-history ring (+1 pad: conflict-free row reads)
    __shared__ float woLDS[2 * HH];       // Wo staged for broadcast reads in flush

    // ---- stage x (coalesced float4), Wo ----
    {
        const float4* xp4 = reinterpret_cast<const float4*>(x + (size_t)b * (TT * 2));
        float4*       xs4 = reinterpret_cast<float4*>(xs);
#pragma unroll
        for (int i = 0; i < (TT * 2 / 4) / 64; ++i) xs4[j + 64 * i] = xp4[j + 64 * i];
    }
    for (int i = j; i < 2 * HH; i += 64) woLDS[i] = Wo[i];

    // ---- all weights in-register: lane j holds row j of every matrix, packed fp16 pairs ----
    // w5: a, p1, p2, f_h, g_h (h-part);  wfu/wgu: u-part of Wf/Wg
    half2v w5[5][32], wfu[32], wgu[32];
    {
        const float* Wsrc[5] = {Wa, Wp1, Wp2, Wf, Wg};
        const int    ldv[5]  = {HH + 1, HH + 1, HH + 1, 2 * HH, 2 * HH};
#pragma unroll
        for (int g = 0; g < 5; ++g) {
            const float* r = Wsrc[g] + (size_t)j * ldv[g];
#pragma unroll
            for (int m = 0; m < 32; ++m) w5[g][m] = pack_pair(r[2 * m], r[2 * m + 1]);
        }
        const float* rf = Wf + (size_t)j * (2 * HH) + HH;
        const float* rg = Wg + (size_t)j * (2 * HH) + HH;
#pragma unroll
        for (int m = 0; m < 32; ++m) {
            wfu[m] = pack_pair(rf[2 * m], rf[2 * m + 1]);
            wgu[m] = pack_pair(rg[2 * m], rg[2 * m + 1]);
        }
#pragma unroll
        for (int g = 0; g < 5; ++g)
#pragma unroll
            for (int m = 0; m < 32; ++m) pin_h2(w5[g][m]);
#pragma unroll
        for (int m = 0; m < 32; ++m) { pin_h2(wfu[m]); pin_h2(wgu[m]); }
    }

    const float waX  = Wa [j * (HH + 1) + HH];
    const float wp1X = Wp1[j * (HH + 1) + HH];
    const float wp2X = Wp2[j * (HH + 1) + HH];
    const float ba_r = ba[j], bp1_r = bp1[j], bp2_r = bp2[j];
    const float bf_r = bf[j], bg_r = bg[j];
    const float bo0  = bo[0], bo1 = bo[1];

    float  h  = h0[b * HH + j];
    float* yp = out + (size_t)b * (TT * 2);

    __syncthreads();   // single wave: near-free; orders staging

    // x-scalar pipeline for t=0 (amp/cos/sin via one rsq)
    float amp, ct, st;
    {
        float xi = xs[0], xq = xs[1];
        float r2 = xi * xi + xq * xq;
        float rq = fast_rsq(r2);
        bool ok = r2 > 0.f;
        amp = ok ? r2 * rq : 0.f;
        ct  = ok ? xi * rq : 1.f;   // cos(atan2(q,i)); atan2(0,0)=0
        st  = ok ? xq * rq : 0.f;
    }

    for (int t = 0; t < TT; ++t) {
        // next step's x scalars (independent: fills latency slots)
        const int tn = (t + 1 < TT) ? (t + 1) : t;
        float xi_n = xs[2 * tn], xq_n = xs[2 * tn + 1];
        float amp_n, ct_n, st_n;
        {
            float r2 = xi_n * xi_n + xq_n * xq_n;
            float rq = fast_rsq(r2);
            bool ok = r2 > 0.f;
            amp_n = ok ? r2 * rq : 0.f;
            ct_n  = ok ? xi_n * rq : 1.f;
            st_n  = ok ? xq_n * rq : 0.f;
        }

        // broadcast all 32 h pairs (readlane -> SGPR)
        float  hnbr = dpp_neighbor(h);
        half2v hp   = pack_pair(h, hnbr);
        half2v sh[32];
#pragma unroll
        for (int m = 0; m < 32; ++m) sh[m] = bcast_pair(hp, 2 * m);

        // ---- phase A: all 5 h-matvecs, 5 round-robin chains (dep spacing 10 cyc) ----
        float acc[5];
        acc[0] = fmaf(amp, waX,  ba_r);
        acc[1] = fmaf(ct,  wp1X, bp1_r);
        acc[2] = fmaf(st,  wp2X, bp2_r);
        acc[3] = bf_r;
        acc[4] = bg_r;
#pragma unroll
        for (int m = 0; m < 32; ++m)
#pragma unroll
            for (int g = 0; g < 5; ++g)
                acc[g] = fdot2(sh[m], w5[g][m], acc[g]);

        float av = tanh_fast(acc[0]);
        float p1 = tanh_fast(acc[1]);
        float p2 = tanh_fast(acc[2]);
        // u = a(1-a) * p1(1-p1) * p2(1-p2), each factor one fma
        float u = fmaf(-av, av, av) * fmaf(-p1, p1, p1) * fmaf(-p2, p2, p2);

        // broadcast all 32 u pairs
        float  unbr = dpp_neighbor(u);
        half2v up   = pack_pair(u, unbr);
        half2v su[32];
#pragma unroll
        for (int m = 0; m < 32; ++m) su[m] = bcast_pair(up, 2 * m);

        // ---- phase C: f,g u-parts, 4 chains ----
        float f0 = acc[3], f1 = 0.f, g0 = acc[4], g1 = 0.f;
#pragma unroll
        for (int m = 0; m < 16; ++m) {
            f0 = fdot2(su[m],      wfu[m],      f0);
            f1 = fdot2(su[m + 16], wfu[m + 16], f1);
            g0 = fdot2(su[m],      wgu[m],      g0);
            g1 = fdot2(su[m + 16], wgu[m + 16], g1);
        }
        float f = sigmoid_fast(f0 + f1);
        float g = tanh_fast(g0 + g1);
        h = fmaf(f, h - g, g);   // f*h + (1-f)*g

        // y deferred: 1 conflict-free ds_write per step into the ring
        hbuf[t & 63][j] = h;

        if ((t & 63) == 63) {
            // flush: lane L computes y(t-63+L) in f32; woLDS reads are broadcasts,
            // hbuf reads stride 65 words -> conflict-free
            float y0 = bo0, y1 = bo1;
#pragma unroll 4
            for (int k = 0; k < HH; ++k) {
                float hv = hbuf[j][k];
                y0 = fmaf(hv, woLDS[k],      y0);
                y1 = fmaf(hv, woLDS[HH + k], y1);
            }
            reinterpret_cast<float2*>(yp)[(t - 63) + j] = make_float2(y0, y1);
        }

        amp = amp_n; ct = ct_n; st = st_n;
    }
}

extern "C" void kernel_launch(void* const* d_in, const int* in_sizes, int n_in,
                              void* d_out, int out_size, void* d_ws, size_t ws_size,
                              hipStream_t stream) {
    const float* x   = (const float*)d_in[0];
    const float* h0  = (const float*)d_in[1];
    const float* Wa  = (const float*)d_in[2];
    const float* ba  = (const float*)d_in[3];
    const float* Wp1 = (const float*)d_in[4];
    const float* bp1 = (const float*)d_in[5];
    const float* Wp2 = (const float*)d_in[6];
    const float* bp2 = (const float*)d_in[7];
    const float* Wf  = (const float*)d_in[8];
    const float* bf  = (const float*)d_in[9];
    const float* Wg  = (const float*)d_in[10];
    const float* bg  = (const float*)d_in[11];
    const float* Wo  = (const float*)d_in[12];
    const float* bo  = (const float*)d_in[13];
    float* out = (float*)d_out;

    pgjanet_kernel<<<dim3(BB), dim3(64), 0, stream>>>(
        x, h0, Wa, ba, Wp1, bp1, Wp2, bp2, Wf, bf, Wg, bg, Wo, bo, out);
}